// Round 14
// baseline (269.158 us; speedup 1.0000x reference)
//
#include <hip/hip_runtime.h>
#include <hip/hip_bf16.h>

#define TT 1024
#define KS 64
#define PFD 4   // prefetch depth; t = 1..1024 (t=1024 is a masked dummy), 256 groups of 4

typedef __attribute__((ext_vector_type(8))) short bf16x8;
typedef __attribute__((ext_vector_type(4))) float f32x4;
typedef __attribute__((ext_vector_type(2))) unsigned short u16x2;

__device__ __forceinline__ unsigned short f2bf(float x) {
    union { __hip_bfloat16 h; unsigned short s; } u;
    u.h = __float2bfloat16(x);
    return u.s;
}
__device__ __forceinline__ float bflo(unsigned u) {
    union { unsigned v; float f; } w; w.v = u << 16; return w.f;
}
__device__ __forceinline__ float bfhi(unsigned u) {
    union { unsigned v; float f; } w; w.v = u & 0xFFFF0000u; return w.f;
}
// ---- compiler-friendly packed ops (no inline asm: lets scheduler fuse) ----
__device__ __forceinline__ unsigned cvtpkC(float a, float b) {
    // two RNE f32->bf16 + pack; compiler selects v_cvt_pk_bf16_f32
    return (unsigned)f2bf(a) | ((unsigned)f2bf(b) << 16);
}
__device__ __forceinline__ unsigned pkaddC(unsigned a, unsigned k) {
    u16x2 x = __builtin_bit_cast(u16x2, a);
    u16x2 kk = __builtin_bit_cast(u16x2, k);
    x = x + kk;                         // v_pk_add_u16
    return __builtin_bit_cast(unsigned, x);
}
// ---- asm helpers kept only for the (unused-on-main-path) fallback ----
__device__ __forceinline__ unsigned cvtpk(float a, float b) {
    unsigned r;
    asm("v_cvt_pk_bf16_f32 %0, %1, %2" : "=v"(r) : "v"(a), "v"(b));
    return r;
}
__device__ __forceinline__ unsigned pkadd(unsigned a, unsigned b) {
    unsigned r;
    asm("v_pk_add_u16 %0, %1, %2" : "=v"(r) : "v"(a), "v"(b));
    return r;
}

// ---------------------------------------------------------------------------
// Pre-pass: g = f32 exp(emissions), memory-bound streaming.
// ---------------------------------------------------------------------------
__global__ __launch_bounds__(256) void crf_expem_f32(
    const float* __restrict__ em, float4* __restrict__ g, long long n4)
{
    long long i = (long long)blockIdx.x * blockDim.x + threadIdx.x;
    const long long stride = (long long)gridDim.x * blockDim.x;
    const float4* p = (const float4*)em;
    for (; i < n4; i += stride) {
        float4 a = p[i];
        float4 o;
        o.x = __expf(a.x); o.y = __expf(a.y);
        o.z = __expf(a.z); o.w = __expf(a.w);
        g[i] = o;
    }
}

// ---------------------------------------------------------------------------
// Fused kernel: blocks [0, nZ) run the logZ forward recursion (wave 0 only);
// blocks [nZ, nZ+B) compute the gold path score on otherwise-idle CUs.
//
// logZ: MFMA forward recursion, lane-local repack (verified r7/r8/r11/r13):
//   sigma(m, rr) = 32*(m>>1) + 8*(rr>>2) + 4*(m&1) + (rr&3)
//   af_kk[e] = d_{2kk+(e>>2)}[e&3]  -> zero cross-lane repack.
// r14 changes vs r13 (chain diet, math identical):
//   (a) tail entirely in C (v_pk_mul_f32 / v_cvt_pk_bf16_f32 / v_pk_add_u16
//       selected by the compiler; no inline-asm VALU -> no forced movs),
//   (b) slot refill moved to END of step (no 16-reg slot copy).
// Keep: asm-volatile flat loads (anti-sink, r7 lesson), straight-line while
// loads in flight (r9 lesson), vmcnt(15)+sched_barrier (rule #18), clamped
// tail refills, dummy masked step t=1024, deadbeat measure-once/apply-once
// controller (r10 lesson), M += sln2 exact bookkeeping.
// ---------------------------------------------------------------------------
__global__ __launch_bounds__(256, 1) void crf_fused(
    const float* __restrict__ em,
    const float* __restrict__ gf,       // f32 exp(em), [B][T][K]
    const int* __restrict__ mask,
    const int* __restrict__ tags,
    const float* __restrict__ trans,
    const float* __restrict__ startT,
    const float* __restrict__ endT,
    float* __restrict__ logZ,
    float* __restrict__ gold,
    int nZ)
{
    __shared__ float wacc[4];
    __shared__ int   wcnt[4];

    if ((int)blockIdx.x >= nZ) {
        // ---------------- gold path score (one block per batch) ------------
        const int b = (int)blockIdx.x - nZ;
        const int tid = threadIdx.x;
        const float* emb = em + (size_t)b * TT * KS;
        const int* tb = tags + (size_t)b * TT;
        const int* mb = mask + (size_t)b * TT;

        float acc = 0.f;
        int cnt = 0;
        for (int t = tid; t < TT; t += 256) {
            int tg = tb[t];
            int mv = mb[t];
            float mf = mv ? 1.f : 0.f;
            acc += emb[t * KS + tg] * mf;
            if (t >= 1) acc += trans[tb[t - 1] * KS + tg] * mf;
            cnt += mv ? 1 : 0;
        }
#pragma unroll
        for (int off = 32; off; off >>= 1) {
            acc += __shfl_xor(acc, off);
            cnt += __shfl_xor(cnt, off);
        }
        int wv = tid >> 6;
        if ((tid & 63) == 0) { wacc[wv] = acc; wcnt[wv] = cnt; }
        __syncthreads();
        if (tid == 0) {
            float a = wacc[0] + wacc[1] + wacc[2] + wacc[3];
            int   cc = wcnt[0] + wcnt[1] + wcnt[2] + wcnt[3];
            gold[b] = a + startT[tb[0]] + endT[tb[cc - 1]];
        }
        return;
    }

    // ---------------- logZ forward recursion (wave 0 only) ----------------
    if (threadIdx.x >= 64) return;
    __builtin_amdgcn_s_setprio(1);

    const int l = threadIdx.x;
    const int c = l & 15;
    const int h = l >> 4;
    const long long b = (long long)blockIdx.x * 16 + c;

    // constant transition fragments (A-operand), permuted columns sigma(m,c)
    const int sigc = 8 * (c >> 2) + (c & 3);
    bf16x8 E[4][2];
#pragma unroll
    for (int m = 0; m < 4; ++m) {
        const int col = 32 * (m >> 1) + 4 * (m & 1) + sigc;
#pragma unroll
        for (int kk = 0; kk < 2; ++kk) {
            union { unsigned short s[8]; bf16x8 v; } u;
#pragma unroll
            for (int e = 0; e < 8; ++e)
                u.s[e] = f2bf(__expf(trans[(32 * kk + 8 * h + e) * KS + col]));
            E[m][kk] = u.v;
        }
    }

    const long long embase = b * (long long)TT * KS;
    const unsigned long long gp =
        (unsigned long long)(const void*)((const char*)gf + embase * 4 + h * 32);
    const unsigned long long mp =
        (unsigned long long)(const void*)(mask + b * TT);

    // ---- state init at t=0: aw = bf16(exp(em0_j + start_j)) ----
    unsigned aw0, aw1, aw2, aw3, aw4, aw5, aw6, aw7;
    {
        const float* erow = em + embase;
        float w0[16];
#pragma unroll
        for (int kk = 0; kk < 2; ++kk)
#pragma unroll
            for (int e = 0; e < 8; ++e) {
                const int j = 32 * kk + 8 * h + e;
                w0[8 * kk + e] = __expf(erow[j] + startT[j]);
            }
        aw0 = cvtpkC(w0[0], w0[1]);   aw1 = cvtpkC(w0[2], w0[3]);
        aw2 = cvtpkC(w0[4], w0[5]);   aw3 = cvtpkC(w0[6], w0[7]);
        aw4 = cvtpkC(w0[8], w0[9]);   aw5 = cvtpkC(w0[10], w0[11]);
        aw6 = cvtpkC(w0[12], w0[13]); aw7 = cvtpkC(w0[14], w0[15]);
    }
    float M = 0.f;

    // ---- depth-4 prefetch slots (flat global_load, r8/r11-proven idiom) ----
    f32x4 gA[PFD], gB[PFD], gC[PFD], gD[PFD];
    int   mvp[PFD];
#pragma unroll
    for (int u = 0; u < PFD; ++u) {
        const unsigned long long a  = gp + (unsigned long long)(1 + u) * 256ull;
        const unsigned long long ma = mp + (unsigned long long)(1 + u) * 4ull;
        asm volatile("global_load_dwordx4 %0, %1, off" : "=&v"(gA[u]) : "v"(a));
        asm volatile("global_load_dwordx4 %0, %1, off offset:16" : "=&v"(gB[u]) : "v"(a));
        asm volatile("global_load_dwordx4 %0, %1, off offset:128" : "=&v"(gC[u]) : "v"(a));
        asm volatile("global_load_dwordx4 %0, %1, off offset:144" : "=&v"(gD[u]) : "v"(a));
        asm volatile("global_load_dword %0, %1, off" : "=&v"(mvp[u]) : "v"(ma));
    }

    // ---- deadbeat controller (absolute exponent re-center) ----
    unsigned kadd = 0;
    float    sln2 = 0.f;
#define CRF_CTRL() do {                                                        \
    const unsigned l0 = aw0 & 0xffffu, h0 = aw0 >> 16;                         \
    const unsigned l4 = aw4 & 0xffffu, h4 = aw4 >> 16;                         \
    unsigned um = l0 > h0 ? l0 : h0;                                           \
    um = um > l4 ? um : l4;  um = um > h4 ? um : h4;                           \
    unsigned sx = (unsigned)__shfl_xor((int)um, 16); um = um > sx ? um : sx;   \
    sx = (unsigned)__shfl_xor((int)um, 32);          um = um > sx ? um : sx;   \
    const unsigned k16 = (0x3F80u - (um & 0x7F80u)) & 0xffffu;                 \
    kadd = (k16 << 16) | k16;                                                  \
    sln2 = (float)((int)((um >> 7) & 0xffu) - 127) * 0.693147180559945f;       \
} while (0)

#define CRF_STEP(t, u, APPLY) do {                                             \
    union { unsigned uu[4]; bf16x8 v; } A0, A1;                                \
    A0.uu[0] = aw0; A0.uu[1] = aw1; A0.uu[2] = aw2; A0.uu[3] = aw3;            \
    A1.uu[0] = aw4; A1.uu[1] = aw5; A1.uu[2] = aw6; A1.uu[3] = aw7;            \
    const f32x4 z = {0.f, 0.f, 0.f, 0.f};                                      \
    f32x4 d0 = __builtin_amdgcn_mfma_f32_16x16x32_bf16(E[0][0], A0.v, z,0,0,0);\
    f32x4 d1 = __builtin_amdgcn_mfma_f32_16x16x32_bf16(E[1][0], A0.v, z,0,0,0);\
    f32x4 d2 = __builtin_amdgcn_mfma_f32_16x16x32_bf16(E[2][0], A0.v, z,0,0,0);\
    f32x4 d3 = __builtin_amdgcn_mfma_f32_16x16x32_bf16(E[3][0], A0.v, z,0,0,0);\
    d0 = __builtin_amdgcn_mfma_f32_16x16x32_bf16(E[0][1], A1.v, d0, 0,0,0);    \
    d1 = __builtin_amdgcn_mfma_f32_16x16x32_bf16(E[1][1], A1.v, d1, 0,0,0);    \
    d2 = __builtin_amdgcn_mfma_f32_16x16x32_bf16(E[2][1], A1.v, d2, 0,0,0);    \
    d3 = __builtin_amdgcn_mfma_f32_16x16x32_bf16(E[3][1], A1.v, d3, 0,0,0);    \
    asm volatile("s_waitcnt vmcnt(15)" ::: "memory");                          \
    __builtin_amdgcn_sched_barrier(0);                                         \
    const int mvv = ((t) <= TT - 1) ? mvp[u] : 0;                              \
    const f32x4 p0 = d0 * gA[u];                                               \
    const f32x4 p1 = d1 * gB[u];                                               \
    const f32x4 p2 = d2 * gC[u];                                               \
    const f32x4 p3 = d3 * gD[u];                                               \
    unsigned q0 = cvtpkC(p0[0], p0[1]);                                        \
    unsigned q1 = cvtpkC(p0[2], p0[3]);                                        \
    unsigned q2 = cvtpkC(p1[0], p1[1]);                                        \
    unsigned q3 = cvtpkC(p1[2], p1[3]);                                        \
    unsigned q4 = cvtpkC(p2[0], p2[1]);                                        \
    unsigned q5 = cvtpkC(p2[2], p2[3]);                                        \
    unsigned q6 = cvtpkC(p3[0], p3[1]);                                        \
    unsigned q7 = cvtpkC(p3[2], p3[3]);                                        \
    if (APPLY) {                                                               \
        q0 = pkaddC(q0, kadd); q1 = pkaddC(q1, kadd);                          \
        q2 = pkaddC(q2, kadd); q3 = pkaddC(q3, kadd);                          \
        q4 = pkaddC(q4, kadd); q5 = pkaddC(q5, kadd);                          \
        q6 = pkaddC(q6, kadd); q7 = pkaddC(q7, kadd);                          \
    }                                                                          \
    aw0 = mvv ? q0 : aw0; aw1 = mvv ? q1 : aw1;                                \
    aw2 = mvv ? q2 : aw2; aw3 = mvv ? q3 : aw3;                                \
    aw4 = mvv ? q4 : aw4; aw5 = mvv ? q5 : aw5;                                \
    aw6 = mvv ? q6 : aw6; aw7 = mvv ? q7 : aw7;                                \
    if (APPLY) { M = mvv ? (M + sln2) : M; }                                   \
    {                                                                          \
        const int tn = ((t) + PFD <= TT - 1) ? ((t) + PFD) : (TT - 1);         \
        const unsigned long long a  = gp + (unsigned long long)tn * 256ull;    \
        const unsigned long long ma = mp + (unsigned long long)tn * 4ull;      \
        asm volatile("global_load_dwordx4 %0, %1, off" : "=&v"(gA[u]) : "v"(a)); \
        asm volatile("global_load_dwordx4 %0, %1, off offset:16" : "=&v"(gB[u]) : "v"(a)); \
        asm volatile("global_load_dwordx4 %0, %1, off offset:128" : "=&v"(gC[u]) : "v"(a)); \
        asm volatile("global_load_dwordx4 %0, %1, off offset:144" : "=&v"(gD[u]) : "v"(a)); \
        asm volatile("global_load_dword %0, %1, off" : "=&v"(mvp[u]) : "v"(ma)); \
    }                                                                          \
} while (0)

    // measure after group step 0; apply exactly once at step 2 (deadbeat)
    for (int t0 = 1; t0 < TT + 1; t0 += PFD) {
        CRF_STEP(t0 + 0, 0, 0);
        CRF_CTRL();
        CRF_STEP(t0 + 1, 1, 0);
        CRF_STEP(t0 + 2, 2, 1);
        CRF_STEP(t0 + 3, 3, 0);
    }
#undef CRF_STEP
#undef CRF_CTRL
    __builtin_amdgcn_s_setprio(0);

    // logZ_b = M + log(sum_j w_j * exp(end_j))
    float val = 0.f;
    {
        const unsigned a[8] = {aw0, aw1, aw2, aw3, aw4, aw5, aw6, aw7};
#pragma unroll
        for (int kk = 0; kk < 2; ++kk)
#pragma unroll
            for (int wi = 0; wi < 4; ++wi) {
                const int j0 = 32 * kk + 8 * h + 2 * wi;
                const unsigned wq = a[4 * kk + wi];
                val += bflo(wq) * __expf(endT[j0]);
                val += bfhi(wq) * __expf(endT[j0 + 1]);
            }
    }
    val += __shfl_xor(val, 16);
    val += __shfl_xor(val, 32);
    if (l < 16) logZ[(long long)blockIdx.x * 16 + l] = M + __logf(val);
}

// ---------------------------------------------------------------------------
// Fallback (workspace too small): r7-verified kernel, exp on the fly.
// ---------------------------------------------------------------------------
__global__ __launch_bounds__(64, 1) void crf_logZ_fb(
    const float* __restrict__ em, const int* __restrict__ mask,
    const float* __restrict__ trans, const float* __restrict__ startT,
    const float* __restrict__ endT, float* __restrict__ logZ)
{
    const int l = threadIdx.x;
    const int c = l & 15;
    const int h = l >> 4;
    const long long b = (long long)blockIdx.x * 16 + c;

    const int sigc = 8 * (c >> 2) + (c & 3);
    bf16x8 E[4][2];
#pragma unroll
    for (int m = 0; m < 4; ++m) {
        const int col = 32 * (m >> 1) + 4 * (m & 1) + sigc;
#pragma unroll
        for (int kk = 0; kk < 2; ++kk) {
            union { unsigned short s[8]; bf16x8 v; } u;
#pragma unroll
            for (int e = 0; e < 8; ++e)
                u.s[e] = f2bf(__expf(trans[(32 * kk + 8 * h + e) * KS + col]));
            E[m][kk] = u.v;
        }
    }
    const long long embase = b * (long long)TT * KS;
    const int* mrow = mask + b * TT;
    const float* erow = em + embase;

    unsigned aw[8];
    {
        float w0[16];
#pragma unroll
        for (int kk = 0; kk < 2; ++kk)
#pragma unroll
            for (int e = 0; e < 8; ++e) {
                const int j = 32 * kk + 8 * h + e;
                w0[8 * kk + e] = __expf(erow[j] + startT[j]);
            }
#pragma unroll
        for (int i = 0; i < 8; ++i) aw[i] = cvtpk(w0[2 * i], w0[2 * i + 1]);
    }
    float M = 0.f;

    for (int t = 1; t < TT; ++t) {
        union { unsigned uu[4]; bf16x8 v; } A0, A1;
#pragma unroll
        for (int i = 0; i < 4; ++i) { A0.uu[i] = aw[i]; A1.uu[i] = aw[4 + i]; }
        const f32x4 z = {0.f, 0.f, 0.f, 0.f};
        f32x4 d0 = __builtin_amdgcn_mfma_f32_16x16x32_bf16(E[0][0], A0.v, z,0,0,0);
        f32x4 d1 = __builtin_amdgcn_mfma_f32_16x16x32_bf16(E[1][0], A0.v, z,0,0,0);
        f32x4 d2 = __builtin_amdgcn_mfma_f32_16x16x32_bf16(E[2][0], A0.v, z,0,0,0);
        f32x4 d3 = __builtin_amdgcn_mfma_f32_16x16x32_bf16(E[3][0], A0.v, z,0,0,0);
        d0 = __builtin_amdgcn_mfma_f32_16x16x32_bf16(E[0][1], A1.v, d0, 0,0,0);
        d1 = __builtin_amdgcn_mfma_f32_16x16x32_bf16(E[1][1], A1.v, d1, 0,0,0);
        d2 = __builtin_amdgcn_mfma_f32_16x16x32_bf16(E[2][1], A1.v, d2, 0,0,0);
        d3 = __builtin_amdgcn_mfma_f32_16x16x32_bf16(E[3][1], A1.v, d3, 0,0,0);
        const float r0 = __shfl(d0.x, c);
        float gf[16];
#pragma unroll
        for (int kk = 0; kk < 2; ++kk)
#pragma unroll
            for (int e = 0; e < 8; ++e)
                gf[8 * kk + e] = __expf(erow[(long long)t * KS + 32 * kk + 8 * h + e]);
        const int sh = 127 - (int)((__float_as_uint(r0) >> 23) & 0xff);
        const unsigned k16 = (unsigned)(unsigned short)(sh * 128);
        const unsigned kadd = (k16 << 16) | k16;
        const int mv = mrow[t];
        const f32x4 dd[4] = {d0, d1, d2, d3};
#pragma unroll
        for (int i = 0; i < 8; ++i) {
            const f32x4 dv = dd[i >> 1];
            const float x = (i & 1) ? dv.z : dv.x;
            const float y = (i & 1) ? dv.w : dv.y;
            const unsigned q = pkadd(cvtpk(x * gf[2 * i], y * gf[2 * i + 1]), kadd);
            aw[i] = mv ? q : aw[i];
        }
        M = mv ? (M - (float)sh * 0.693147180559945f) : M;
    }

    float val = 0.f;
#pragma unroll
    for (int kk = 0; kk < 2; ++kk)
#pragma unroll
        for (int wi = 0; wi < 4; ++wi) {
            const int j0 = 32 * kk + 8 * h + 2 * wi;
            const unsigned wq = aw[4 * kk + wi];
            val += bflo(wq) * __expf(endT[j0]);
            val += bfhi(wq) * __expf(endT[j0 + 1]);
        }
    val += __shfl_xor(val, 16);
    val += __shfl_xor(val, 32);
    if (l < 16) logZ[(long long)blockIdx.x * 16 + l] = M + __logf(val);
}

// ---------------------------------------------------------------------------
// Standalone gold (fallback path only).
// ---------------------------------------------------------------------------
__global__ __launch_bounds__(256) void crf_gold_kernel(
    const float* __restrict__ em, const int* __restrict__ tags,
    const int* __restrict__ mask, const float* __restrict__ trans,
    const float* __restrict__ startT, const float* __restrict__ endT,
    float* __restrict__ gold, int T)
{
    const int b = blockIdx.x;
    const int tid = threadIdx.x;
    const float* emb = em + (size_t)b * T * KS;
    const int* tb = tags + (size_t)b * T;
    const int* mb = mask + (size_t)b * T;

    float acc = 0.f;
    int cnt = 0;
    for (int t = tid; t < T; t += 256) {
        int tg = tb[t];
        int mv = mb[t];
        float mf = mv ? 1.f : 0.f;
        acc += emb[t * KS + tg] * mf;
        if (t >= 1) acc += trans[tb[t - 1] * KS + tg] * mf;
        cnt += mv ? 1 : 0;
    }
#pragma unroll
    for (int off = 32; off; off >>= 1) {
        acc += __shfl_xor(acc, off);
        cnt += __shfl_xor(cnt, off);
    }
    __shared__ float wacc[4];
    __shared__ int   wcnt[4];
    int wv = tid >> 6;
    if ((tid & 63) == 0) { wacc[wv] = acc; wcnt[wv] = cnt; }
    __syncthreads();
    if (tid == 0) {
        float a = wacc[0] + wacc[1] + wacc[2] + wacc[3];
        int   cc = wcnt[0] + wcnt[1] + wcnt[2] + wcnt[3];
        gold[b] = a + startT[tb[0]] + endT[tb[cc - 1]];
    }
}

// ---------------------------------------------------------------------------
// mean(logZ - gold) -> scalar
// ---------------------------------------------------------------------------
__global__ __launch_bounds__(512) void crf_reduce_kernel(
    const float* __restrict__ logZ, const float* __restrict__ gold,
    float* __restrict__ out, int B)
{
    int tid = threadIdx.x;
    float v = 0.f;
    for (int i = tid; i < B; i += 512) v += logZ[i] - gold[i];
#pragma unroll
    for (int off = 32; off; off >>= 1) v += __shfl_xor(v, off);
    __shared__ float ws[8];
    int w = tid >> 6;
    if ((tid & 63) == 0) ws[w] = v;
    __syncthreads();
    if (tid == 0) {
        float s = 0.f;
#pragma unroll
        for (int k = 0; k < 8; ++k) s += ws[k];
        out[0] = s / (float)B;
    }
}

// ---------------------------------------------------------------------------
extern "C" void kernel_launch(void* const* d_in, const int* in_sizes, int n_in,
                              void* d_out, int out_size, void* d_ws, size_t ws_size,
                              hipStream_t stream)
{
    const float* emissions = (const float*)d_in[0];
    const int*   tags      = (const int*)d_in[1];
    const int*   mask      = (const int*)d_in[2];
    const float* trans     = (const float*)d_in[3];
    const float* startT    = (const float*)d_in[4];
    const float* endT      = (const float*)d_in[5];

    const int T = TT;
    const int B = in_sizes[1] / T;

    float* logZ = (float*)d_ws;
    float* gold = logZ + B;

    const size_t g32 = (size_t)B * T * KS * 4;

    if (ws_size >= 8192 + g32 && (B % 16) == 0) {
        float4* g = (float4*)((char*)d_ws + 8192);
        const int nZ = B / 16;
        crf_expem_f32<<<2048, 256, 0, stream>>>(
            emissions, g, (long long)B * T * KS / 4);
        crf_fused<<<nZ + B, 256, 0, stream>>>(
            emissions, (const float*)g, mask, tags, trans, startT, endT,
            logZ, gold, nZ);
    } else {
        crf_logZ_fb<<<B / 16, 64, 0, stream>>>(
            emissions, mask, trans, startT, endT, logZ);
        crf_gold_kernel<<<B, 256, 0, stream>>>(
            emissions, tags, mask, trans, startT, endT, gold, T);
    }
    crf_reduce_kernel<<<1, 512, 0, stream>>>(logZ, gold, (float*)d_out, B);
}